// Round 1
// 689.102 us; speedup vs baseline: 1.0030x; 1.0030x over previous
//
#include <hip/hip_runtime.h>
#include <stdint.h>

#define B_TOT 8192
#define F 64
#define D 256
#define NPAIR 2016
#define PITCH 264           // bf16 elems per LDS row: 256 + 8 pad; 528 B row stride
                            // -> 8 consecutive lanes (8 rows, same 16B slot) hit 8
                            //    distinct bank-quads: conflict-free ds_read_b128
#define CHUNK 16            // batches per block
#define NBLK (B_TOT / CHUNK)  // 512 blocks = 2/CU x 256 CU, fully persistent
#define NTHR 512            // 8 waves

typedef __bf16 bf16x8 __attribute__((ext_vector_type(8)));
typedef __bf16 bf16x4 __attribute__((ext_vector_type(4)));
typedef float f32x4 __attribute__((ext_vector_type(4)));

__global__ __launch_bounds__(NTHR, 4)   // 4 waves/EU = 16 waves/CU (2 blocks/CU by LDS)
void DotInteraction_kernel(const float* __restrict__ X, float* __restrict__ out)
{
    // double-buffered bf16 staging: 2 x 64 rows x 264 = 67.6 KB
    __shared__ unsigned short sX[2][F * PITCH];

    const int tid = threadIdx.x;
    const int b0 = blockIdx.x * CHUNK;

    // ---- prologue: stage batch b0 into buffer 0 (coalesced float4 stream)
    {
        const float4* __restrict__ src = (const float4*)(X + (size_t)b0 * (F * D));
        float4 r[8];
#pragma unroll
        for (int it = 0; it < 8; ++it) r[it] = src[it * NTHR + tid];
#pragma unroll
        for (int it = 0; it < 8; ++it) {
            const int v   = it * NTHR + tid;   // float4 index into the batch
            const int row = v >> 6;            // 64 float4s per row
            const int col = (v & 63) << 2;     // element column
            float4 f = r[it];
            bf16x4 h = { (__bf16)f.x, (__bf16)f.y, (__bf16)f.z, (__bf16)f.w };
            *(bf16x4*)&sX[0][row * PITCH + col] = h;   // 8B store, 8B aligned
        }
    }

    const int wave = tid >> 6;
    const int lane = tid & 63;
    const int r16  = lane & 15;
    const int quad = lane >> 4;

    for (int c = 0; c < CHUNK; ++c) {
        const unsigned short* __restrict__ cur = sX[c & 1];

        // separates prev iter's LDS writes/reads from this iter's reads/writes
        __syncthreads();

        // ---- issue-early: prefetch batch c+1 into registers (in flight across MFMA)
        float4 r[8];
        const bool pf = (c + 1 < CHUNK);
        if (pf) {
            const float4* __restrict__ src =
                (const float4*)(X + (size_t)(b0 + c + 1) * (F * D));
#pragma unroll
            for (int it = 0; it < 8; ++it) r[it] = src[it * NTHR + tid];
        }

        // ---- compute: 10 upper-tri 16x16 tiles of the 64x64 Gram, over 8 waves
        float* __restrict__ ob = out + (size_t)(b0 + c) * NPAIR;
        for (int t = wave; t < 10; t += 8) {
            int ti, tj;
            if      (t < 4) { ti = 0; tj = t; }
            else if (t < 7) { ti = 1; tj = t - 3; }
            else if (t < 9) { ti = 2; tj = t - 5; }
            else            { ti = 3; tj = 3; }

            f32x4 acc = {0.f, 0.f, 0.f, 0.f};
            // A[m][k]: m = lane&15 -> row ti*16+m, k = quad*8 + kk*32 + j
            // B[k][n]: n = lane&15 -> B[k][n] = X[tj*16+n][k] (Gram: B = A^T read)
            const unsigned short* pa = &cur[(ti * 16 + r16) * PITCH + quad * 8];
            const unsigned short* pb = &cur[(tj * 16 + r16) * PITCH + quad * 8];
#pragma unroll
            for (int kk = 0; kk < 8; ++kk) {
                bf16x8 a  = *(const bf16x8*)(pa + kk * 32);   // 16B ds_read_b128
                bf16x8 bb = *(const bf16x8*)(pb + kk * 32);
                acc = __builtin_amdgcn_mfma_f32_16x16x32_bf16(a, bb, acc, 0, 0, 0);
            }

            // C/D layout: col = lane&15, row = quad*4 + reg  [verified mapping]
            const int j = tj * 16 + r16;
#pragma unroll
            for (int rr = 0; rr < 4; ++rr) {
                const int i = ti * 16 + quad * 4 + rr;
                if (j > i) {
                    const int p = (i * (127 - i)) / 2 + (j - i - 1);
                    ob[p] = acc[rr];
                }
            }
        }

        // ---- write-late: convert prefetched regs -> other LDS buffer.
        // vmcnt waits land here, after the MFMA phase covered the HBM latency.
        if (pf) {
            unsigned short* __restrict__ nxt = sX[(c + 1) & 1];
#pragma unroll
            for (int it = 0; it < 8; ++it) {
                const int v   = it * NTHR + tid;
                const int row = v >> 6;
                const int col = (v & 63) << 2;
                float4 f = r[it];
                bf16x4 h = { (__bf16)f.x, (__bf16)f.y, (__bf16)f.z, (__bf16)f.w };
                *(bf16x4*)&nxt[row * PITCH + col] = h;
            }
        }
    }
}

extern "C" void kernel_launch(void* const* d_in, const int* in_sizes, int n_in,
                              void* d_out, int out_size, void* d_ws, size_t ws_size,
                              hipStream_t stream) {
    const float* X = (const float*)d_in[0];
    float* out = (float*)d_out;
    DotInteraction_kernel<<<NBLK, NTHR, 0, stream>>>(X, out);
}